// Round 3
// baseline (20298.500 us; speedup 1.0000x reference)
//
#include <hip/hip_runtime.h>

typedef short v8s __attribute__((ext_vector_type(8)));
typedef float v4f __attribute__((ext_vector_type(4)));

constexpr int nB = 32, nT = 2048, nI = 256, nH = 512, nC = 64;
constexpr int NBLK = 32;               // one block per 16 hidden units
// LDS layout (bytes), recurrent kernel:
constexpr int WHH_OFF = 0;             // [64][512] bf16, 64KB, swizzled
constexpr int WIH_OFF = 65536;         // [64][256] bf16, 32KB, swizzled
constexpr int HS_OFF  = 98304;         // [32][512] bf16, 32KB, swizzled
constexpr int XS_OFF  = 131072;        // [32][256] bf16, 16KB, swizzled
constexpr int RED_OFF = 147456;        // [2][4][16][16] f32, 8KB
constexpr int LDS_REC = 155648;        // 152KB <= 160KB/WG on gfx950

__device__ __forceinline__ int swz(int byte, int row) { return byte ^ ((row & 7) << 4); }

__device__ __forceinline__ unsigned short f2bf(float f) {   // RNE float->bf16
  union { float f; unsigned u; } v; v.f = f;
  unsigned r = v.u + 0x7FFFu + ((v.u >> 16) & 1u);
  return (unsigned short)(r >> 16);
}
__device__ __forceinline__ unsigned pk2(float a, float b) {
  return (unsigned)f2bf(a) | ((unsigned)f2bf(b) << 16);
}
__device__ __forceinline__ float sigm(float x) { return 1.0f / (1.0f + __expf(-x)); }
__device__ __forceinline__ float tanh_(float x) { return 1.0f - 2.0f / (__expf(2.0f * x) + 1.0f); }

// Persistent recurrent kernel: 32 blocks x 256 threads (4 waves).
// wave w: mt = w&1 (batch half), kh = w>>1 (K half). Block bid owns hidden
// units [bid*16, bid*16+16) -> gate rows {g*512 + j} for g in {i,f,g,o}.
// Local gate index n = g*16 + jj so that acc[nt] == gate type nt (lane-local
// i,f,g,o in the pointwise phase -> no cross-lane gate shuffle).
__global__ void __launch_bounds__(256, 1)
lstm_rec_kernel(const float* __restrict__ inp, const float* __restrict__ hnoise,
                const float* __restrict__ cnoise, const float* __restrict__ Wih,
                const float* __restrict__ Whh, const float* __restrict__ bih,
                const float* __restrict__ bhh, unsigned short* __restrict__ hseq,
                int* __restrict__ flags)
{
  extern __shared__ char sm[];
  const int tid = threadIdx.x, bid = blockIdx.x;
  const int lane = tid & 63, w = tid >> 6;
  const int mt = w & 1, kh = w >> 1;
  const int l15 = lane & 15, l4 = lane >> 4;
  const int j0 = bid * 16;

  // ---- stage weight slices to LDS (bf16, swizzled); one-time ----
  for (int c = tid; c < 64 * 64; c += 256) {            // Whh: 64 rows x 64 8-elem chunks
    int n = c >> 6, k8 = c & 63;
    int grow = (n >> 4) * nH + j0 + (n & 15);
    const float4* s4 = (const float4*)(Whh + (size_t)grow * nH + k8 * 8);
    float4 a = s4[0], b = s4[1];
    uint4 p = { pk2(a.x, a.y), pk2(a.z, a.w), pk2(b.x, b.y), pk2(b.z, b.w) };
    *(uint4*)(sm + WHH_OFF + swz(n * 1024 + k8 * 16, n)) = p;
  }
  for (int c = tid; c < 64 * 32; c += 256) {            // Wih: 64 rows x 32 chunks
    int n = c >> 5, k8 = c & 31;
    int grow = (n >> 4) * nH + j0 + (n & 15);
    const float4* s4 = (const float4*)(Wih + (size_t)grow * nI + k8 * 8);
    float4 a = s4[0], b = s4[1];
    uint4 p = { pk2(a.x, a.y), pk2(a.z, a.w), pk2(b.x, b.y), pk2(b.z, b.w) };
    *(uint4*)(sm + WIH_OFF + swz(n * 512 + k8 * 16, n)) = p;
  }
  __syncthreads();

  // ---- B-fragments (weights) permanently in registers: 48 frags = 192 VGPR ----
  v8s bx[4][4], bh[4][8];
#pragma unroll
  for (int nt = 0; nt < 4; ++nt) {
    int n = nt * 16 + l15;
#pragma unroll
    for (int i = 0; i < 4; ++i) {
      int kk = kh * 4 + i;
      bx[nt][i] = *(const v8s*)(sm + WIH_OFF + swz(n * 512 + kk * 64 + l4 * 16, n));
    }
#pragma unroll
    for (int i = 0; i < 8; ++i) {
      int kk = kh * 8 + i;
      bh[nt][i] = *(const v8s*)(sm + WHH_OFF + swz(n * 1024 + kk * 64 + l4 * 16, n));
    }
  }

  float bias[4];
#pragma unroll
  for (int g = 0; g < 4; ++g)
    bias[g] = bih[g * nH + j0 + l15] + bhh[g * nH + j0 + l15];

  float creg[4] = {0.f, 0.f, 0.f, 0.f};                 // fp32 cell state, register-resident

  // ---- h_0 = 0 (each block writes its own 16 columns for all 32 batches) ----
  if (kh == 0) {
#pragma unroll
    for (int r = 0; r < 4; ++r) {
      int b = mt * 16 + l4 * 4 + r;
      hseq[(size_t)b * nH + j0 + l15] = 0;
    }
  }
  __syncthreads();                                      // drains vmcnt for all waves
  if (tid == 0) {
    __threadfence();                                    // release: wbl2 -> LLC
    __hip_atomic_exchange(flags + (size_t)bid * 32, 1, __ATOMIC_RELAXED,
                          __HIP_MEMORY_SCOPE_AGENT);
  }

  for (int t = 0; t < nT; ++t) {
    // ---- stage X_t -> LDS bf16 (no dependence on h; overlaps the flag wait) ----
#pragma unroll
    for (int j = 0; j < 8; ++j) {
      int idx = tid + j * 256;                          // 2048 float4 chunks
      int b = idx >> 6, wi = idx & 63;
      float4 v = *(const float4*)(inp + ((size_t)b * nT + t) * nI + wi * 4);
      uint2 p = { pk2(v.x, v.y), pk2(v.z, v.w) };
      *(uint2*)(sm + XS_OFF + swz(b * 512 + wi * 8, b)) = p;
    }
    // ---- prefetch noise for this step (kh0 waves consume it) ----
    float hn[4] = {0, 0, 0, 0}, cn[4] = {0, 0, 0, 0};
    if (kh == 0) {
#pragma unroll
      for (int r = 0; r < 4; ++r) {
        int b = mt * 16 + l4 * 4 + r;
        size_t off = (size_t)t * nB * nH + (size_t)b * nH + j0 + l15;
        hn[r] = hnoise[off];
        cn[r] = cnoise[off];
      }
    }
    // ---- wait until all blocks published h_t (flags >= t+1) ----
    if (tid < NBLK) {
      while (__hip_atomic_fetch_add(flags + (size_t)tid * 32, 0, __ATOMIC_RELAXED,
                                    __HIP_MEMORY_SCOPE_AGENT) < t + 1) {
        __builtin_amdgcn_s_sleep(1);
      }
    }
    __syncthreads();
    __threadfence();                                    // acquire: inv L1/L2

    // ---- stage h_t -> LDS bf16 (swizzled) ----
    {
      const uint4* src = (const uint4*)(hseq + (size_t)t * nB * nH);
#pragma unroll
      for (int j = 0; j < 8; ++j) {
        int c = tid + j * 256;                          // 2048 16B chunks
        int row = c >> 6;
        uint4 v = src[c];
        *(uint4*)(sm + HS_OFF + swz(c * 16, row)) = v;
      }
    }
    __syncthreads();

    // ---- gates GEMM: [32,64] += X[32,256]@WihT + h[32,512]@WhhT (K-half per wave) ----
    v4f acc[4];
#pragma unroll
    for (int nt = 0; nt < 4; ++nt) acc[nt] = (v4f){0.f, 0.f, 0.f, 0.f};
    {
      int arow = mt * 16 + l15;
#pragma unroll
      for (int i = 0; i < 4; ++i) {
        int kk = kh * 4 + i;
        v8s a = *(const v8s*)(sm + XS_OFF + swz(arow * 512 + kk * 64 + l4 * 16, arow));
        acc[0] = __builtin_amdgcn_mfma_f32_16x16x32_bf16(a, bx[0][i], acc[0], 0, 0, 0);
        acc[1] = __builtin_amdgcn_mfma_f32_16x16x32_bf16(a, bx[1][i], acc[1], 0, 0, 0);
        acc[2] = __builtin_amdgcn_mfma_f32_16x16x32_bf16(a, bx[2][i], acc[2], 0, 0, 0);
        acc[3] = __builtin_amdgcn_mfma_f32_16x16x32_bf16(a, bx[3][i], acc[3], 0, 0, 0);
      }
#pragma unroll
      for (int i = 0; i < 8; ++i) {
        int kk = kh * 8 + i;
        v8s a = *(const v8s*)(sm + HS_OFF + swz(arow * 1024 + kk * 64 + l4 * 16, arow));
        acc[0] = __builtin_amdgcn_mfma_f32_16x16x32_bf16(a, bh[0][i], acc[0], 0, 0, 0);
        acc[1] = __builtin_amdgcn_mfma_f32_16x16x32_bf16(a, bh[1][i], acc[1], 0, 0, 0);
        acc[2] = __builtin_amdgcn_mfma_f32_16x16x32_bf16(a, bh[2][i], acc[2], 0, 0, 0);
        acc[3] = __builtin_amdgcn_mfma_f32_16x16x32_bf16(a, bh[3][i], acc[3], 0, 0, 0);
      }
    }
    // ---- cross-wave K reduction (kh=1 writes, kh=0 adds) ----
    if (kh == 1) {
#pragma unroll
      for (int nt = 0; nt < 4; ++nt)
#pragma unroll
        for (int r = 0; r < 4; ++r) {
          int m = l4 * 4 + r;
          *(float*)(sm + RED_OFF + (((mt * 4 + nt) * 16 + m) * 16 + l15) * 4) = acc[nt][r];
        }
    }
    __syncthreads();
    if (kh == 0) {
#pragma unroll
      for (int nt = 0; nt < 4; ++nt)
#pragma unroll
        for (int r = 0; r < 4; ++r) {
          int m = l4 * 4 + r;
          acc[nt][r] += *(const float*)(sm + RED_OFF + (((mt * 4 + nt) * 16 + m) * 16 + l15) * 4);
        }
      // ---- LSTM pointwise: lane-local i,f,g,o (acc[0..3]); fp32 cell state ----
      unsigned short hob[4];
#pragma unroll
      for (int r = 0; r < 4; ++r) {
        float i_ = sigm(acc[0][r] + bias[0]);
        float f_ = sigm(acc[1][r] + bias[1]);
        float g_ = tanh_(acc[2][r] + bias[2]);
        float o_ = sigm(acc[3][r] + bias[3]);
        float c_ = f_ * creg[r] + i_ * g_;
        float h_ = o_ * tanh_(c_) + hn[r];              // noise AFTER cell update
        creg[r] = c_ + cn[r];
        hob[r] = f2bf(h_);
      }
#pragma unroll
      for (int r = 0; r < 4; ++r) {
        int b = mt * 16 + l4 * 4 + r;
        hseq[(size_t)(t + 1) * nB * nH + (size_t)b * nH + j0 + l15] = hob[r];
      }
    }
    __syncthreads();                                    // drains vmcnt: h stores in L2
    if (tid == 0) {
      __threadfence();                                  // release: wbl2 -> LLC
      __hip_atomic_exchange(flags + (size_t)bid * 32, t + 2, __ATOMIC_RELAXED,
                            __HIP_MEMORY_SCOPE_AGENT);
    }
  }
}

// Head: logits = h_seq[1:] @ W_final^T + b_final, then log_softmax over C=64.
// 1024 blocks x 256 threads; wave owns 16 rows; W_final bf16 in LDS (swizzled).
__global__ void __launch_bounds__(256)
lstm_head_kernel(const unsigned short* __restrict__ hseq, const float* __restrict__ Wf,
                 const float* __restrict__ bfin_g, float* __restrict__ out)
{
  extern __shared__ char sm[];
  const int tid = threadIdx.x, lane = tid & 63, w = tid >> 6;
  const int l15 = lane & 15, l4 = lane >> 4;

  for (int c = tid; c < 64 * 64; c += 256) {            // Wf [64][512] -> bf16 LDS
    int n = c >> 6, k8 = c & 63;
    const float4* s4 = (const float4*)(Wf + (size_t)n * nH + k8 * 8);
    float4 a = s4[0], b = s4[1];
    uint4 p = { pk2(a.x, a.y), pk2(a.z, a.w), pk2(b.x, b.y), pk2(b.z, b.w) };
    *(uint4*)(sm + swz(n * 1024 + k8 * 16, n)) = p;
  }
  __syncthreads();

  float bfin[4];
#pragma unroll
  for (int nt = 0; nt < 4; ++nt) bfin[nt] = bfin_g[nt * 16 + l15];

  const int R0 = blockIdx.x * 64 + w * 16;              // output row base (row = t*32+b)
  v4f acc[4];
#pragma unroll
  for (int nt = 0; nt < 4; ++nt) acc[nt] = (v4f){0.f, 0.f, 0.f, 0.f};

  const unsigned short* arow = hseq + ((size_t)R0 + l15 + nB) * nH;  // +nB: skip h_0
#pragma unroll
  for (int kk = 0; kk < 16; ++kk) {
    v8s a = *(const v8s*)(arow + kk * 32 + l4 * 8);
#pragma unroll
    for (int nt = 0; nt < 4; ++nt) {
      int n = nt * 16 + l15;
      v8s b = *(const v8s*)(sm + swz(n * 1024 + kk * 64 + l4 * 16, n));
      acc[nt] = __builtin_amdgcn_mfma_f32_16x16x32_bf16(a, b, acc[nt], 0, 0, 0);
    }
  }

#pragma unroll
  for (int r = 0; r < 4; ++r) {
    int R = R0 + l4 * 4 + r;
    int t = R >> 5, b = R & 31;
    float v0 = acc[0][r] + bfin[0], v1 = acc[1][r] + bfin[1];
    float v2 = acc[2][r] + bfin[2], v3 = acc[3][r] + bfin[3];
    float mx = fmaxf(fmaxf(v0, v1), fmaxf(v2, v3));
#pragma unroll
    for (int s = 1; s < 16; s <<= 1) mx = fmaxf(mx, __shfl_xor(mx, s, 16));
    float sum = __expf(v0 - mx) + __expf(v1 - mx) + __expf(v2 - mx) + __expf(v3 - mx);
#pragma unroll
    for (int s = 1; s < 16; s <<= 1) sum += __shfl_xor(sum, s, 16);
    float lz = logf(sum);
    float* o = out + ((size_t)b * nT + t) * nC;
    o[0 * 16 + l15] = v0 - mx - lz;
    o[1 * 16 + l15] = v1 - mx - lz;
    o[2 * 16 + l15] = v2 - mx - lz;
    o[3 * 16 + l15] = v3 - mx - lz;
  }
}

extern "C" void kernel_launch(void* const* d_in, const int* in_sizes, int n_in,
                              void* d_out, int out_size, void* d_ws, size_t ws_size,
                              hipStream_t stream) {
  (void)in_sizes; (void)n_in; (void)out_size; (void)ws_size;
  const float* inp    = (const float*)d_in[0];
  const float* hnoise = (const float*)d_in[1];
  const float* cnoise = (const float*)d_in[2];
  const float* Wih    = (const float*)d_in[3];
  const float* Whh    = (const float*)d_in[4];
  const float* bih    = (const float*)d_in[5];
  const float* bhh    = (const float*)d_in[6];
  const float* Wf     = (const float*)d_in[7];
  const float* bfin   = (const float*)d_in[8];
  float* out = (float*)d_out;

  // Dynamic-LDS opt-in: 152KB > the 64KB default cap on some ROCm versions.
  // Host-side attribute set (no stream work) -> graph-capture-safe, idempotent.
  (void)hipFuncSetAttribute((const void*)lstm_rec_kernel,
                            hipFuncAttributeMaxDynamicSharedMemorySize, LDS_REC);
  (void)hipFuncSetAttribute((const void*)lstm_head_kernel,
                            hipFuncAttributeMaxDynamicSharedMemorySize, 65536);

  // workspace: h_seq [T+1][B][H] bf16 (67,141,632 B) then 32 flags, 128B apart.
  unsigned short* hseq = (unsigned short*)d_ws;
  int* flags = (int*)((char*)d_ws + (size_t)(nT + 1) * nB * nH * 2);

  hipLaunchKernelGGL(lstm_rec_kernel, dim3(NBLK), dim3(256), LDS_REC, stream,
                     inp, hnoise, cnoise, Wih, Whh, bih, bhh, hseq, flags);
  hipLaunchKernelGGL(lstm_head_kernel, dim3((nB * nT) / 64), dim3(256), 65536, stream,
                     hseq, Wf, bfin, out);
}

// Round 6
// 13322.893 us; speedup vs baseline: 1.5236x; 1.5236x over previous
//
#include <hip/hip_runtime.h>

typedef short v8s __attribute__((ext_vector_type(8)));
typedef float v4f __attribute__((ext_vector_type(4)));

constexpr int nB = 32, nT = 2048, nI = 256, nH = 512, nC = 64;

__device__ __forceinline__ int swz(int byte, int row) { return byte ^ ((row & 7) << 4); }

__device__ __forceinline__ unsigned short f2bf(float f) {   // RNE float->bf16
  union { float f; unsigned u; } v; v.f = f;
  unsigned r = v.u + 0x7FFFu + ((v.u >> 16) & 1u);
  return (unsigned short)(r >> 16);
}
__device__ __forceinline__ unsigned pk2(float a, float b) {
  return (unsigned)f2bf(a) | ((unsigned)f2bf(b) << 16);
}
__device__ __forceinline__ v8s pack8(float4 a, float4 b) {
  union { unsigned u[4]; v8s v; } r;
  r.u[0] = pk2(a.x, a.y); r.u[1] = pk2(a.z, a.w);
  r.u[2] = pk2(b.x, b.y); r.u[3] = pk2(b.z, b.w);
  return r.v;
}
__device__ __forceinline__ float sigm(float x) { return 1.0f / (1.0f + __expf(-x)); }
__device__ __forceinline__ float tanh_(float x) { return 1.0f - 2.0f / (__expf(2.0f * x) + 1.0f); }

// Persistent recurrent kernel: 128 blocks x 64 threads = 128 INDEPENDENT waves.
// wave wid: bid = wid>>2 (hidden-unit group of 16), mt = wid&1 (batch half),
// np = (wid>>1)&1 (which 8 of the block's 16 hidden units).
// Wave computes batches [mt*16,mt*16+16) x 32 gate-cols (4 gates x 8 units) as
// 2 MFMA N-tiles: acc0 = gates {i,f}, acc1 = {g,o}; lanes l15<8 hold (i,g),
// lanes>=8 hold (f,o) for the same unit jj. One shfl_xor(8) pairs all four
// gates lane-locally; fp32 cell state lives in registers.
//
// Zero LDS, zero barriers. All h traffic via relaxed agent-scope atomics
// (serviced at the device coherence point): producers store h as atomic dwords,
// ack with vmcnt(0), then publish their own flag (flags[mt*64+np*32+bid]).
// Consumers poll their mt-group's 64 flags with one coalesced atomic load, then
// read h_t with atomic 8B loads (address data-depends on the polled value so
// the compiler cannot hoist them above the poll). Max flag skew across waves
// is provably <=1 step, so dep==0 always.
__global__ void __launch_bounds__(64, 1)
lstm_rec_kernel(const float* __restrict__ inp, const float* __restrict__ hnoise,
                const float* __restrict__ cnoise, const float* __restrict__ Wih,
                const float* __restrict__ Whh, const float* __restrict__ bih,
                const float* __restrict__ bhh, unsigned short* __restrict__ hseq,
                int* flags)
{
  const int lane = threadIdx.x & 63;
  const int wid = blockIdx.x;
  const int bid = wid >> 2, mt = wid & 1, np = (wid >> 1) & 1;
  const int l15 = lane & 15, l4 = lane >> 4;
  const int j0 = bid * 16;
  const int jj = np * 8 + (l15 & 7);                    // this lane's hidden unit (block-local)

  // ---- one-time: B-fragments (weights) straight from global into registers ----
  v8s bh[2][16], bx[2][8];
#pragma unroll
  for (int nt2 = 0; nt2 < 2; ++nt2) {
    int g = nt2 * 2 + (l15 >> 3);                       // gate for this lane's B-column
    size_t grow = (size_t)g * nH + j0 + jj;             // row of [4H, *] weight
    const float* wr = Whh + grow * nH;
#pragma unroll
    for (int kk = 0; kk < 16; ++kk)
      bh[nt2][kk] = pack8(*(const float4*)(wr + kk * 32 + l4 * 8),
                          *(const float4*)(wr + kk * 32 + l4 * 8 + 4));
    const float* wr2 = Wih + grow * nI;
#pragma unroll
    for (int kk = 0; kk < 8; ++kk)
      bx[nt2][kk] = pack8(*(const float4*)(wr2 + kk * 32 + l4 * 8),
                          *(const float4*)(wr2 + kk * 32 + l4 * 8 + 4));
  }
  float b_i = bih[0 * nH + j0 + jj] + bhh[0 * nH + j0 + jj];
  float b_f = bih[1 * nH + j0 + jj] + bhh[1 * nH + j0 + jj];
  float b_g = bih[2 * nH + j0 + jj] + bhh[2 * nH + j0 + jj];
  float b_o = bih[3 * nH + j0 + jj] + bhh[3 * nH + j0 + jj];
  const float biasA = (l15 & 8) ? b_f : b_i;            // bias of acc0's column
  const float biasB = (l15 & 8) ? b_o : b_g;            // bias of acc1's column

  // ---- h_0 = 0 for this wave's own cells; ack; publish flag=1 ----
  if (l15 < 8 && !(l15 & 1)) {
#pragma unroll
    for (int r = 0; r < 4; ++r)
      __hip_atomic_store((unsigned*)(hseq + (size_t)(mt * 16 + l4 * 4 + r) * nH + j0 + np * 8 + l15),
                         0u, __ATOMIC_RELAXED, __HIP_MEMORY_SCOPE_AGENT);
  }
  asm volatile("s_waitcnt vmcnt(0)" ::: "memory");
  __builtin_amdgcn_sched_barrier(0);
  if (lane == 0)
    __hip_atomic_store(&flags[mt * 64 + np * 32 + bid], 1, __ATOMIC_RELAXED,
                       __HIP_MEMORY_SCOPE_AGENT);

  // ---- initial prefetch (t=0): x fragments (fp32) + noise, into registers ----
  uint4 xpre[16];
  {
    const float* xr = inp + ((size_t)(mt * 16 + l15) * nT + 0) * nI;
#pragma unroll
    for (int kk = 0; kk < 8; ++kk) {
      xpre[2 * kk]     = *(const uint4*)(xr + kk * 32 + l4 * 8);
      xpre[2 * kk + 1] = *(const uint4*)(xr + kk * 32 + l4 * 8 + 4);
    }
  }
  float hn[4], cn[4];
#pragma unroll
  for (int r = 0; r < 4; ++r) {
    size_t off = (size_t)(mt * 16 + l4 * 4 + r) * nH + j0 + jj;  // t=0
    hn[r] = hnoise[off]; cn[r] = cnoise[off];
  }

  float creg[4] = {0.f, 0.f, 0.f, 0.f};

  for (int t = 0; t < nT; ++t) {
    // (1) x-part MFMAs (h-independent; runs before the wait)
    v4f acc0 = {biasA, biasA, biasA, biasA};
    v4f acc1 = {biasB, biasB, biasB, biasB};
#pragma unroll
    for (int kk = 0; kk < 8; ++kk) {
      union { uint4 q; float f[4]; } lo, hi;
      lo.q = xpre[2 * kk]; hi.q = xpre[2 * kk + 1];
      union { unsigned u[4]; v8s v; } av;
      av.u[0] = pk2(lo.f[0], lo.f[1]); av.u[1] = pk2(lo.f[2], lo.f[3]);
      av.u[2] = pk2(hi.f[0], hi.f[1]); av.u[3] = pk2(hi.f[2], hi.f[3]);
      acc0 = __builtin_amdgcn_mfma_f32_16x16x32_bf16(av.v, bx[0][kk], acc0, 0, 0, 0);
      acc1 = __builtin_amdgcn_mfma_f32_16x16x32_bf16(av.v, bx[1][kk], acc1, 0, 0, 0);
    }

    // (2) poll my mt-group's 64 flags: one coalesced atomic dword load / round
    int fv;
    while (true) {
      fv = __hip_atomic_load(&flags[mt * 64 + lane], __ATOMIC_RELAXED, __HIP_MEMORY_SCOPE_AGENT);
      if (__all(fv >= t + 1)) break;
      __builtin_amdgcn_s_sleep(1);
    }
    __builtin_amdgcn_sched_barrier(0);
    int dep = (fv - (t + 1)) >> 2;                      // provably 0 (skew<=1), data-dep on fv

    // (3) h_t A-fragments: relaxed agent-scope 8B atomic loads (LLC-serviced)
    const char* hb = (const char*)(hseq + ((size_t)t * nB + mt * 16 + l15) * nH) + dep;
    unsigned long long hlo[16], hhi[16];
#pragma unroll
    for (int kk = 0; kk < 16; ++kk) {
      hlo[kk] = __hip_atomic_load((const unsigned long long*)(hb + kk * 64 + l4 * 16),
                                  __ATOMIC_RELAXED, __HIP_MEMORY_SCOPE_AGENT);
      hhi[kk] = __hip_atomic_load((const unsigned long long*)(hb + kk * 64 + l4 * 16 + 8),
                                  __ATOMIC_RELAXED, __HIP_MEMORY_SCOPE_AGENT);
    }
    // (4) h-part MFMAs
#pragma unroll
    for (int kk = 0; kk < 16; ++kk) {
      union { unsigned long long q[2]; v8s v; } av;
      av.q[0] = hlo[kk]; av.q[1] = hhi[kk];
      acc0 = __builtin_amdgcn_mfma_f32_16x16x32_bf16(av.v, bh[0][kk], acc0, 0, 0, 0);
      acc1 = __builtin_amdgcn_mfma_f32_16x16x32_bf16(av.v, bh[1][kk], acc1, 0, 0, 0);
    }

    // (5) pointwise: pair gates across lanes l15 <-> l15+8, compute 4 cells
    float fo0[4], fo1[4];
#pragma unroll
    for (int r = 0; r < 4; ++r) fo0[r] = __shfl_xor(acc0[r], 8, 64);
#pragma unroll
    for (int r = 0; r < 4; ++r) fo1[r] = __shfl_xor(acc1[r], 8, 64);
    float hval[4] = {0.f, 0.f, 0.f, 0.f};
    if (l15 < 8) {
#pragma unroll
      for (int r = 0; r < 4; ++r) {
        float iv  = sigm(acc0[r]);                      // own: gate i (+bias folded)
        float fvg = sigm(fo0[r]);                       // partner: gate f
        float gv  = tanh_(acc1[r]);                     // own: gate g
        float ov  = sigm(fo1[r]);                       // partner: gate o
        float cnew = fvg * creg[r] + iv * gv;
        hval[r] = ov * tanh_(cnew) + hn[r];             // noise AFTER cell update
        creg[r] = cnew + cn[r];
      }
    }
    // pack (jj, jj+1) via shfl_xor(1); even lanes store device-visible dwords
    float hpar[4];
#pragma unroll
    for (int r = 0; r < 4; ++r) hpar[r] = __shfl_xor(hval[r], 1, 64);
    if (l15 < 8 && !(l15 & 1)) {
#pragma unroll
      for (int r = 0; r < 4; ++r) {
        unsigned d = pk2(hval[r], hpar[r]);
        int b = mt * 16 + l4 * 4 + r;
        __hip_atomic_store((unsigned*)(hseq + ((size_t)(t + 1) * nB + b) * nH + j0 + np * 8 + l15),
                           d, __ATOMIC_RELAXED, __HIP_MEMORY_SCOPE_AGENT);
      }
    }

    // (6) ack own h stores; publish own flag (no barrier — waves independent)
    asm volatile("s_waitcnt vmcnt(0)" ::: "memory");
    __builtin_amdgcn_sched_barrier(0);
    if (lane == 0)
      __hip_atomic_store(&flags[mt * 64 + np * 32 + bid], t + 2, __ATOMIC_RELAXED,
                         __HIP_MEMORY_SCOPE_AGENT);

    // (7) prefetch x + noise for t+1 (in flight across next poll)
    if (t + 1 < nT) {
      const float* xr = inp + ((size_t)(mt * 16 + l15) * nT + (t + 1)) * nI;
#pragma unroll
      for (int kk = 0; kk < 8; ++kk) {
        xpre[2 * kk]     = *(const uint4*)(xr + kk * 32 + l4 * 8);
        xpre[2 * kk + 1] = *(const uint4*)(xr + kk * 32 + l4 * 8 + 4);
      }
#pragma unroll
      for (int r = 0; r < 4; ++r) {
        size_t off = ((size_t)(t + 1) * nB + mt * 16 + l4 * 4 + r) * nH + j0 + jj;
        hn[r] = hnoise[off]; cn[r] = cnoise[off];
      }
    }
  }
}

// Head: logits = h_seq[1:] @ W_final^T + b_final, then log_softmax over C=64.
// 1024 blocks x 256 threads; wave owns 16 rows; W_final bf16 in LDS (swizzled).
__global__ void __launch_bounds__(256)
lstm_head_kernel(const unsigned short* __restrict__ hseq, const float* __restrict__ Wf,
                 const float* __restrict__ bfin_g, float* __restrict__ out)
{
  extern __shared__ char sm[];
  const int tid = threadIdx.x, lane = tid & 63, w = tid >> 6;
  const int l15 = lane & 15, l4 = lane >> 4;

  for (int c = tid; c < 64 * 64; c += 256) {            // Wf [64][512] -> bf16 LDS
    int n = c >> 6, k8 = c & 63;
    const float4* s4 = (const float4*)(Wf + (size_t)n * nH + k8 * 8);
    float4 a = s4[0], b = s4[1];
    uint4 p = { pk2(a.x, a.y), pk2(a.z, a.w), pk2(b.x, b.y), pk2(b.z, b.w) };
    *(uint4*)(sm + swz(n * 1024 + k8 * 16, n)) = p;
  }
  __syncthreads();

  float bfin[4];
#pragma unroll
  for (int nt = 0; nt < 4; ++nt) bfin[nt] = bfin_g[nt * 16 + l15];

  const int R0 = blockIdx.x * 64 + w * 16;              // output row base (row = t*32+b)
  v4f acc[4];
#pragma unroll
  for (int nt = 0; nt < 4; ++nt) acc[nt] = (v4f){0.f, 0.f, 0.f, 0.f};

  const unsigned short* arow = hseq + ((size_t)R0 + l15 + nB) * nH;  // +nB: skip h_0
#pragma unroll
  for (int kk = 0; kk < 16; ++kk) {
    v8s a = *(const v8s*)(arow + kk * 32 + l4 * 8);
#pragma unroll
    for (int nt = 0; nt < 4; ++nt) {
      int n = nt * 16 + l15;
      v8s b = *(const v8s*)(sm + swz(n * 1024 + kk * 64 + l4 * 16, n));
      acc[nt] = __builtin_amdgcn_mfma_f32_16x16x32_bf16(a, b, acc[nt], 0, 0, 0);
    }
  }

#pragma unroll
  for (int r = 0; r < 4; ++r) {
    int R = R0 + l4 * 4 + r;
    int t = R >> 5, b = R & 31;
    float v0 = acc[0][r] + bfin[0], v1 = acc[1][r] + bfin[1];
    float v2 = acc[2][r] + bfin[2], v3 = acc[3][r] + bfin[3];
    float mx = fmaxf(fmaxf(v0, v1), fmaxf(v2, v3));
#pragma unroll
    for (int s = 1; s < 16; s <<= 1) mx = fmaxf(mx, __shfl_xor(mx, s, 16));
    float sum = __expf(v0 - mx) + __expf(v1 - mx) + __expf(v2 - mx) + __expf(v3 - mx);
#pragma unroll
    for (int s = 1; s < 16; s <<= 1) sum += __shfl_xor(sum, s, 16);
    float lz = logf(sum);
    float* o = out + ((size_t)b * nT + t) * nC;
    o[0 * 16 + l15] = v0 - mx - lz;
    o[1 * 16 + l15] = v1 - mx - lz;
    o[2 * 16 + l15] = v2 - mx - lz;
    o[3 * 16 + l15] = v3 - mx - lz;
  }
}

extern "C" void kernel_launch(void* const* d_in, const int* in_sizes, int n_in,
                              void* d_out, int out_size, void* d_ws, size_t ws_size,
                              hipStream_t stream) {
  (void)in_sizes; (void)n_in; (void)out_size; (void)ws_size;
  const float* inp    = (const float*)d_in[0];
  const float* hnoise = (const float*)d_in[1];
  const float* cnoise = (const float*)d_in[2];
  const float* Wih    = (const float*)d_in[3];
  const float* Whh    = (const float*)d_in[4];
  const float* bih    = (const float*)d_in[5];
  const float* bhh    = (const float*)d_in[6];
  const float* Wf     = (const float*)d_in[7];
  const float* bfin   = (const float*)d_in[8];
  float* out = (float*)d_out;

  (void)hipFuncSetAttribute((const void*)lstm_head_kernel,
                            hipFuncAttributeMaxDynamicSharedMemorySize, 65536);

  // workspace: h_seq [T+1][B][H] bf16 (67,141,632 B) then 128 wave-flags.
  unsigned short* hseq = (unsigned short*)d_ws;
  int* flags = (int*)((char*)d_ws + (size_t)(nT + 1) * nB * nH * 2);

  hipLaunchKernelGGL(lstm_rec_kernel, dim3(128), dim3(64), 0, stream,
                     inp, hnoise, cnoise, Wih, Whh, bih, bhh, hseq, flags);
  hipLaunchKernelGGL(lstm_head_kernel, dim3((nB * nT) / 64), dim3(256), 65536, stream,
                     hseq, Wf, bfin, out);
}